// Round 4
// baseline (347.019 us; speedup 1.0000x reference)
//
#include <hip/hip_runtime.h>
#include <hip/hip_bf16.h>

typedef _Float16 h8 __attribute__((ext_vector_type(8)));
typedef _Float16 h4v __attribute__((ext_vector_type(4)));
typedef float f4 __attribute__((ext_vector_type(4)));

#define T_ 4
#define B_ 8
#define N_ 512
#define C_ 512
#define H_ 8
#define D_ 64
#define BNR 4096
#define EPSf 1e-5f
#define F16_MIN_NORM 6.1035156e-05f
#define INV4096 0.000244140625f

// ---- fp32 -> (h1 + 2^-12 * h2) f16 split, 4 elements/thread ----
__global__ __launch_bounds__(256)
void split_f16(const float* __restrict__ in, _Float16* __restrict__ h1,
               _Float16* __restrict__ h2, int n4)
{
    int i = blockIdx.x * 256 + threadIdx.x;
    if (i >= n4) return;
    float4 x = reinterpret_cast<const float4*>(in)[i];
    h4v a, b;
    #pragma unroll
    for (int j = 0; j < 4; ++j) {
        float xv = (&x.x)[j];
        float hi = (fabsf(xv) >= F16_MIN_NORM) ? xv : 0.0f;   // avoid f16 subnormal x1
        _Float16 h = (_Float16)hi;
        float r = (xv - (float)h) * 4096.0f;                  // normal-range residual
        a[j] = h; b[j] = (_Float16)r;
    }
    reinterpret_cast<h4v*>(h1)[i] = a;
    reinterpret_cast<h4v*>(h2)[i] = b;
}

// ---- W -> split + MFMA-fragment-linear pack ----
// Wp[ct][ks][ni][lane][8 halves]: lane l holds W[(ct*64+ni*16+(l&15))*512 + ks*32+(l>>4)*8 ..+8]
// so a GEMM W-frag load is 64 lanes x 16B CONTIGUOUS (1KB coalesced, no gather).
__global__ __launch_bounds__(256)
void pack_w(const float* __restrict__ W, _Float16* __restrict__ Wp1,
            _Float16* __restrict__ Wp2)
{
    const int gid = blockIdx.x * 256 + threadIdx.x;   // 32768 items
    const int lane = gid & 63;
    const int ni = (gid >> 6) & 3;
    const int ks = (gid >> 8) & 15;
    const int ct = gid >> 12;
    const int col = ct * 64 + ni * 16 + (lane & 15);
    const int k = ks * 32 + (lane >> 4) * 8;
    const float* src = W + (size_t)col * C_ + k;
    h8 a, b;
    #pragma unroll
    for (int j = 0; j < 8; ++j) {
        float xv = src[j];
        float hi = (fabsf(xv) >= F16_MIN_NORM) ? xv : 0.0f;
        _Float16 h = (_Float16)hi;
        float r = (xv - (float)h) * 4096.0f;
        a[j] = h; b[j] = (_Float16)r;
    }
    *reinterpret_cast<h8*>(Wp1 + (size_t)gid * 8) = a;
    *reinterpret_cast<h8*>(Wp2 + (size_t)gid * 8) = b;
}

// ---- MFMA GEMM (f16 split) + BN(eval) + LIF over T, epilogue-free ----
// Block: 64 bn-rows x 64 cols x 4t. Wave w owns rows [16w,16w+16) for ALL 4 t.
// A staged via global_load_lds (16B) into [q][lane][16B] linear slots, dbuf.
// W frags read DIRECT from packed global (coalesced 1KB), register-prefetched
// one k-step ahead (drained by the same per-step vmcnt(0)+barrier as the A gll).
// MODE 0: A=(A1,A2) split, 3 mfma/frag, out bf16 head-split (T,B,H,N,D).
// MODE 1: A=A1 exact f16 spikes, 2 mfma/frag, out fp32 (T,B,N,C).
template<int MODE>
__global__ __launch_bounds__(256, 2)
void mfma_gemm_bn_lif(const _Float16* __restrict__ A1, const _Float16* __restrict__ A2,
                      const _Float16* __restrict__ Wp1, const _Float16* __restrict__ Wp2,
                      const float* __restrict__ bias, const float* __restrict__ gam,
                      const float* __restrict__ bet, const float* __restrict__ mea,
                      const float* __restrict__ rva,
                      __hip_bfloat16* __restrict__ out_hs, float* __restrict__ out_plain)
{
    constexpr int ABUF = (MODE == 0) ? 32768 : 16384;   // bytes per k-step A buffer
    constexpr int NP = ABUF / 4096;                     // gll iterations (8 / 4)
    __shared__ __align__(16) char smem[2 * ABUF];

    const int tid = threadIdx.x;
    const int id = blockIdx.x;
    const int bt = (id & 7) * 8 + ((id >> 3) & 7);      // XCD-aware swizzle
    const int ct = id >> 6;
    const int row0 = bt * 64, col0 = ct * 64;
    const int wv = tid >> 6, lane = tid & 63;
    const int lr = lane & 15, lk = lane >> 4;

    f4 accA[4][4], accB[4][4];
    #pragma unroll
    for (int t = 0; t < 4; ++t)
        #pragma unroll
        for (int ni = 0; ni < 4; ++ni) { accA[t][ni] = (f4)0.0f; accB[t][ni] = (f4)0.0f; }

    auto stage = [&](int ks, int b) {                   // A k-slice -> LDS buffer b
        #pragma unroll
        for (int p = 0; p < NP; ++p) {
            const int q = p * 4 + wv;                   // slot = q*1024 + lane*16
            const int kq = q & 3, t = (q >> 2) & 3, spl = q >> 4;
            const _Float16* src = (MODE == 0 && spl) ? A2 : A1;
            const _Float16* g = src + (size_t)(t * BNR + row0 + lane) * C_ + ks * 32 + kq * 8;
            char* dst = smem + b * ABUF + p * 4096 + wv * 1024;   // wave-uniform base
            __builtin_amdgcn_global_load_lds(
                (const __attribute__((address_space(1))) unsigned int*)g,
                (__attribute__((address_space(3))) unsigned int*)dst, 16, 0, 0);
        }
    };
    auto loadW = [&](int ks, h8* w1f, h8* w2f) {        // coalesced packed frags
        const size_t base = (size_t)(ct * 16 + ks) * 2048 + lane * 8;
        #pragma unroll
        for (int ni = 0; ni < 4; ++ni) {
            w1f[ni] = *reinterpret_cast<const h8*>(Wp1 + base + ni * 512);
            w2f[ni] = *reinterpret_cast<const h8*>(Wp2 + base + ni * 512);
        }
    };

    h8 wc1[4], wc2[4], wn1[4], wn2[4];
    stage(0, 0);
    loadW(0, wc1, wc2);
    int buf = 0;
    #pragma unroll
    for (int ks = 0; ks < 16; ++ks) {
        __syncthreads();                                // A[buf]+wc ready (vmcnt drain)
        if (ks < 15) {
            stage(ks + 1, buf ^ 1);                     // prefetch next A k-slice
            loadW(ks + 1, wn1, wn2);                    // prefetch next W frags
        }
        const char* ab = smem + buf * ABUF;
        h8 a1[4], a2[4];
        #pragma unroll
        for (int t = 0; t < 4; ++t) {
            const int ao = t * 4096 + lk * 1024 + (wv * 16 + lr) * 16;
            a1[t] = *reinterpret_cast<const h8*>(ab + ao);
            if (MODE == 0) a2[t] = *reinterpret_cast<const h8*>(ab + 16384 + ao);
        }
        #pragma unroll
        for (int ni = 0; ni < 4; ++ni)
            #pragma unroll
            for (int t = 0; t < 4; ++t) {
                accA[t][ni] = __builtin_amdgcn_mfma_f32_16x16x32_f16(a1[t], wc1[ni], accA[t][ni], 0, 0, 0);
                accB[t][ni] = __builtin_amdgcn_mfma_f32_16x16x32_f16(a1[t], wc2[ni], accB[t][ni], 0, 0, 0);
                if (MODE == 0)
                    accB[t][ni] = __builtin_amdgcn_mfma_f32_16x16x32_f16(a2[t], wc1[ni], accB[t][ni], 0, 0, 0);
            }
        if (ks < 15) {
            #pragma unroll
            for (int ni = 0; ni < 4; ++ni) { wc1[ni] = wn1[ni]; wc2[ni] = wn2[ni]; }
        }
        buf ^= 1;
    }

    // ---- in-register BN + LIF epilogue (wave owns all 4 t of its rows) ----
    #pragma unroll
    for (int ni = 0; ni < 4; ++ni) {
        const int c = col0 + ni * 16 + lr;
        const float sc = gam[c] * (1.0f / sqrtf(rva[c] + EPSf));
        const float bi = bias[c], mn = mea[c], be = bet[c];
        #pragma unroll
        for (int r = 0; r < 4; ++r) {
            const int bn = row0 + wv * 16 + lk * 4 + r;  // C/D: row=(l>>4)*4+reg, col=l&15
            float vm = 0.0f;
            #pragma unroll
            for (int t = 0; t < 4; ++t) {
                const float res = accA[t][ni][r] + INV4096 * accB[t][ni][r];
                const float y = ((res + bi) - mn) * sc + be;
                vm = vm + (y - vm) * 0.5f;
                const float s = (vm >= 1.0f) ? 1.0f : 0.0f;
                vm = (s != 0.0f) ? 0.0f : vm;
                if (MODE == 0) {
                    const int b = bn >> 9, n = bn & 511;
                    out_hs[((((size_t)t * B_ + b) * H_ + ct) * N_ + n) * D_ + ni * 16 + lr] =
                        __float2bfloat16(s);
                } else {
                    out_plain[((size_t)t * BNR + bn) * C_ + c] = s;
                }
            }
        }
    }
}

// ---- kv[d1][d2] = sum_n k[n,d1]*v[n,d2] per (t,b,h) ----
__global__ __launch_bounds__(256)
void ktv_kernel(const __hip_bfloat16* __restrict__ sk, const __hip_bfloat16* __restrict__ sv,
                float* __restrict__ kv)
{
    __shared__ __hip_bfloat16 kl[64][64];
    __shared__ __hip_bfloat16 vl[64][64];
    const int tbh = blockIdx.x;
    const int tid = threadIdx.x;
    const int tx = tid & 15, ty = tid >> 4;
    const size_t base = (size_t)tbh * N_ * D_;
    float acc[4][4] = {};
    for (int n0 = 0; n0 < N_; n0 += 64) {
        __syncthreads();
        #pragma unroll
        for (int p = 0; p < 2; ++p) {
            const int idx = tid + p * 256;
            const int r = idx >> 3, c8 = (idx & 7) * 8;
            *reinterpret_cast<float4*>(&kl[r][c8]) =
                *reinterpret_cast<const float4*>(&sk[base + (size_t)(n0 + r) * D_ + c8]);
            *reinterpret_cast<float4*>(&vl[r][c8]) =
                *reinterpret_cast<const float4*>(&sv[base + (size_t)(n0 + r) * D_ + c8]);
        }
        __syncthreads();
        for (int nn = 0; nn < 64; ++nn) {
            float a[4], b[4];
            #pragma unroll
            for (int i = 0; i < 4; ++i) a[i] = __bfloat162float(kl[nn][ty * 4 + i]);
            #pragma unroll
            for (int j = 0; j < 4; ++j) b[j] = __bfloat162float(vl[nn][tx * 4 + j]);
            #pragma unroll
            for (int i = 0; i < 4; ++i)
                #pragma unroll
                for (int j = 0; j < 4; ++j)
                    acc[i][j] = fmaf(a[i], b[j], acc[i][j]);
        }
    }
    float* out = kv + (size_t)tbh * 4096;
    #pragma unroll
    for (int i = 0; i < 4; ++i)
        #pragma unroll
        for (int j = 0; j < 4; ++j)
            out[(ty * 4 + i) * 64 + tx * 4 + j] = acc[i][j];
}

// ---- o = 0.125 * q @ kv, fused attn-LIF (vth=0.5); writes f16 spikes (T,B,N,C) ----
__global__ __launch_bounds__(256)
void qkv_lif_kernel(const __hip_bfloat16* __restrict__ sq, const float* __restrict__ kv,
                    _Float16* __restrict__ osp)
{
    __shared__ float kvl[64][64];
    __shared__ __hip_bfloat16 ql[64][64];
    const int nt = blockIdx.x, b = blockIdx.y, h = blockIdx.z;
    const int tid = threadIdx.x;
    const int tx = tid & 15, ty = tid >> 4;
    const int n0 = nt * 64;
    float v[4][4] = {};
    for (int t = 0; t < T_; ++t) {
        const int tbh = (t * B_ + b) * H_ + h;
        __syncthreads();
        #pragma unroll
        for (int p = 0; p < 16; ++p) {
            const int idx = p * 256 + tid;
            kvl[idx >> 6][idx & 63] = kv[(size_t)tbh * 4096 + idx];
        }
        #pragma unroll
        for (int p = 0; p < 2; ++p) {
            const int idx = tid + p * 256;
            const int r = idx >> 3, c8 = (idx & 7) * 8;
            *reinterpret_cast<float4*>(&ql[r][c8]) =
                *reinterpret_cast<const float4*>(&sq[((size_t)tbh * N_ + n0 + r) * D_ + c8]);
        }
        __syncthreads();
        float acc[4][4] = {};
        for (int dd = 0; dd < 64; ++dd) {
            float a[4], bb[4];
            #pragma unroll
            for (int i = 0; i < 4; ++i) a[i] = __bfloat162float(ql[ty * 4 + i][dd]);
            #pragma unroll
            for (int j = 0; j < 4; ++j) bb[j] = kvl[dd][tx * 4 + j];
            #pragma unroll
            for (int i = 0; i < 4; ++i)
                #pragma unroll
                for (int j = 0; j < 4; ++j)
                    acc[i][j] = fmaf(a[i], bb[j], acc[i][j]);
        }
        #pragma unroll
        for (int i = 0; i < 4; ++i)
            #pragma unroll
            for (int j = 0; j < 4; ++j) {
                const float y = 0.125f * acc[i][j];     // exact (integer counts)
                float vv = v[i][j];
                vv = vv + (y - vv) * 0.5f;
                const float s = (vv >= 0.5f) ? 1.0f : 0.0f;
                osp[((size_t)(t * B_ + b) * N_ + n0 + ty * 4 + i) * C_ + h * 64 + tx * 4 + j] = (_Float16)s;
                v[i][j] = (s != 0.0f) ? 0.0f : vv;
            }
    }
}

extern "C" void kernel_launch(void* const* d_in, const int* in_sizes, int n_in,
                              void* d_out, int out_size, void* d_ws, size_t ws_size,
                              hipStream_t stream)
{
    const float* x = (const float*)d_in[0];
    const float *W[4], *bia[4], *gam[4], *bet[4], *mea[4], *rva[4];
    for (int br = 0; br < 4; ++br) {
        W[br]   = (const float*)d_in[1 + 6 * br + 0];
        bia[br] = (const float*)d_in[1 + 6 * br + 1];
        gam[br] = (const float*)d_in[1 + 6 * br + 2];
        bet[br] = (const float*)d_in[1 + 6 * br + 3];
        mea[br] = (const float*)d_in[1 + 6 * br + 4];
        rva[br] = (const float*)d_in[1 + 6 * br + 5];
    }
    char* ws = (char*)d_ws;
    _Float16* x1 = (_Float16*)(ws + 0);
    _Float16* x2 = (_Float16*)(ws + 16777216);
    __hip_bfloat16* sq = (__hip_bfloat16*)(ws + 33554432);
    __hip_bfloat16* sk = (__hip_bfloat16*)(ws + 50331648);
    __hip_bfloat16* sv = (__hip_bfloat16*)(ws + 67108864);
    _Float16* w1[4], *w2[4];
    for (int br = 0; br < 4; ++br) {
        w1[br] = (_Float16*)(ws + 83886080 + (size_t)br * 1048576);
        w2[br] = (_Float16*)(ws + 83886080 + (size_t)br * 1048576 + 524288);
    }
    float*    kv  = (float*)(ws + 16777216);     // aliases x2 (dead after 3rd GEMM)
    _Float16* osp = (_Float16*)(ws + 0);         // aliases x1 (dead after 3rd GEMM)

    dim3 blk(256);
    split_f16<<<dim3(8192), blk, 0, stream>>>(x, x1, x2, 2097152);
    for (int br = 0; br < 4; ++br)
        pack_w<<<dim3(128), blk, 0, stream>>>(W[br], w1[br], w2[br]);

    mfma_gemm_bn_lif<0><<<dim3(512), blk, 0, stream>>>(x1, x2, w1[0], w2[0],
        bia[0], gam[0], bet[0], mea[0], rva[0], sq, nullptr);
    mfma_gemm_bn_lif<0><<<dim3(512), blk, 0, stream>>>(x1, x2, w1[1], w2[1],
        bia[1], gam[1], bet[1], mea[1], rva[1], sk, nullptr);
    mfma_gemm_bn_lif<0><<<dim3(512), blk, 0, stream>>>(x1, x2, w1[2], w2[2],
        bia[2], gam[2], bet[2], mea[2], rva[2], sv, nullptr);

    ktv_kernel<<<dim3(T_ * B_ * H_), blk, 0, stream>>>(sk, sv, kv);
    qkv_lif_kernel<<<dim3(N_ / 64, B_, H_), blk, 0, stream>>>(sq, kv, osp);

    mfma_gemm_bn_lif<1><<<dim3(512), blk, 0, stream>>>(osp, nullptr, w1[3], w2[3],
        bia[3], gam[3], bet[3], mea[3], rva[3], nullptr, (float*)d_out);
}

// Round 5
// 219.727 us; speedup vs baseline: 1.5793x; 1.5793x over previous
//
#include <hip/hip_runtime.h>
#include <hip/hip_bf16.h>

typedef _Float16 h8 __attribute__((ext_vector_type(8)));
typedef _Float16 h4v __attribute__((ext_vector_type(4)));
typedef float f4 __attribute__((ext_vector_type(4)));

#define T_ 4
#define B_ 8
#define N_ 512
#define C_ 512
#define H_ 8
#define D_ 64
#define BNR 4096
#define EPSf 1e-5f
#define F16_MIN_NORM 6.1035156e-05f
#define INV4096 0.000244140625f

// ---- fp32 -> (h1 + 2^-12 * h2) f16 split, 4 elements/thread ----
__global__ __launch_bounds__(256)
void split_f16(const float* __restrict__ in, _Float16* __restrict__ h1,
               _Float16* __restrict__ h2, int n4)
{
    int i = blockIdx.x * 256 + threadIdx.x;
    if (i >= n4) return;
    float4 x = reinterpret_cast<const float4*>(in)[i];
    h4v a, b;
    #pragma unroll
    for (int j = 0; j < 4; ++j) {
        float xv = (&x.x)[j];
        float hi = (fabsf(xv) >= F16_MIN_NORM) ? xv : 0.0f;   // avoid f16 subnormal x1
        _Float16 h = (_Float16)hi;
        float r = (xv - (float)h) * 4096.0f;                  // normal-range residual
        a[j] = h; b[j] = (_Float16)r;
    }
    reinterpret_cast<h4v*>(h1)[i] = a;
    reinterpret_cast<h4v*>(h2)[i] = b;
}

// ---- W -> split + MFMA-fragment-linear pack ----
// Wp[ct][ks][ni][lane][8 halves]: lane l holds W[(ct*64+ni*16+(l&15))*512 + ks*32+(l>>4)*8 ..+8]
__global__ __launch_bounds__(256)
void pack_w(const float* __restrict__ W, _Float16* __restrict__ Wp1,
            _Float16* __restrict__ Wp2)
{
    const int gid = blockIdx.x * 256 + threadIdx.x;   // 32768 items
    const int lane = gid & 63;
    const int ni = (gid >> 6) & 3;
    const int ks = (gid >> 8) & 15;
    const int ct = gid >> 12;
    const int col = ct * 64 + ni * 16 + (lane & 15);
    const int k = ks * 32 + (lane >> 4) * 8;
    const float* src = W + (size_t)col * C_ + k;
    h8 a, b;
    #pragma unroll
    for (int j = 0; j < 8; ++j) {
        float xv = src[j];
        float hi = (fabsf(xv) >= F16_MIN_NORM) ? xv : 0.0f;
        _Float16 h = (_Float16)hi;
        float r = (xv - (float)h) * 4096.0f;
        a[j] = h; b[j] = (_Float16)r;
    }
    *reinterpret_cast<h8*>(Wp1 + (size_t)gid * 8) = a;
    *reinterpret_cast<h8*>(Wp2 + (size_t)gid * 8) = b;
}

// ---- MFMA GEMM (f16 split) + BN(eval) + LIF over T, epilogue-free ----
// Block: 64 bn-rows x 64 cols x 4t. Wave w owns rows [16w,16w+16) for ALL 4 t.
// A AND W staged via global_load_lds (16B, linear slots), double-buffered, one
// barrier per k-step (stage(next) issued before compute). W frags read from
// LDS once per step (32 regs); A frags read per-t (8 regs) -> no spill.
// MODE 0: A=(A1,A2) split, 3 mfma/frag, out bf16 head-split (T,B,H,N,D).
// MODE 1: A=A1 exact f16 spikes, 2 mfma/frag, out fp32 (T,B,N,C).
template<int MODE>
__global__ __launch_bounds__(256, 2)
void mfma_gemm_bn_lif(const _Float16* __restrict__ A1, const _Float16* __restrict__ A2,
                      const _Float16* __restrict__ Wp1, const _Float16* __restrict__ Wp2,
                      const float* __restrict__ bias, const float* __restrict__ gam,
                      const float* __restrict__ bet, const float* __restrict__ mea,
                      const float* __restrict__ rva,
                      __hip_bfloat16* __restrict__ out_hs, float* __restrict__ out_plain)
{
    constexpr int ABUF = (MODE == 0) ? 32768 : 16384;   // bytes per k-step A buffer
    constexpr int NP = ABUF / 4096;                     // A gll instrs/thread (8 / 4)
    constexpr int WOFF = 2 * ABUF;                      // W region start
    __shared__ __align__(16) char smem[2 * ABUF + 16384];

    const int tid = threadIdx.x;
    const int id = blockIdx.x;
    const int bt = (id & 7) * 8 + ((id >> 3) & 7);      // XCD-aware swizzle
    const int ct = id >> 6;
    const int row0 = bt * 64, col0 = ct * 64;
    const int wv = tid >> 6, lane = tid & 63;
    const int lr = lane & 15, lk = lane >> 4;

    f4 accA[4][4], accB[4][4];
    #pragma unroll
    for (int t = 0; t < 4; ++t)
        #pragma unroll
        for (int ni = 0; ni < 4; ++ni) { accA[t][ni] = (f4)0.0f; accB[t][ni] = (f4)0.0f; }

    auto stage = [&](int ks, int b) {                   // A k-slice -> LDS buffer b
        #pragma unroll
        for (int p = 0; p < NP; ++p) {
            const int q = p * 4 + wv;                   // slot = q*1024 + lane*16
            const int kq = q & 3, t = (q >> 2) & 3, spl = q >> 4;
            const _Float16* src = (MODE == 0 && spl) ? A2 : A1;
            const _Float16* g = src + (size_t)(t * BNR + row0 + lane) * C_ + ks * 32 + kq * 8;
            char* dst = smem + b * ABUF + p * 4096 + wv * 1024;   // wave-uniform base
            __builtin_amdgcn_global_load_lds(
                (const __attribute__((address_space(1))) unsigned int*)g,
                (__attribute__((address_space(3))) unsigned int*)dst, 16, 0, 0);
        }
    };
    auto stageW = [&](int ks, int b) {                  // packed W slice -> LDS
        #pragma unroll
        for (int s = 0; s < 2; ++s) {
            const _Float16* src = (s ? Wp2 : Wp1) + (size_t)(ct * 16 + ks) * 2048
                                  + wv * 512 + lane * 8;
            char* dst = smem + WOFF + b * 8192 + s * 4096 + wv * 1024;
            __builtin_amdgcn_global_load_lds(
                (const __attribute__((address_space(1))) unsigned int*)src,
                (__attribute__((address_space(3))) unsigned int*)dst, 16, 0, 0);
        }
    };

    stage(0, 0);
    stageW(0, 0);
    for (int ks = 0; ks < 16; ++ks) {
        const int buf = ks & 1;
        __syncthreads();                                // drains stage(ks) (vmcnt 0)
        if (ks < 15) { stage(ks + 1, buf ^ 1); stageW(ks + 1, buf ^ 1); }

        const char* wb = smem + WOFF + buf * 8192;
        h8 wf1[4], wf2[4];
        #pragma unroll
        for (int ni = 0; ni < 4; ++ni) {
            wf1[ni] = *reinterpret_cast<const h8*>(wb + ni * 1024 + lane * 16);
            wf2[ni] = *reinterpret_cast<const h8*>(wb + 4096 + ni * 1024 + lane * 16);
        }
        const char* ab = smem + buf * ABUF;
        #pragma unroll
        for (int t = 0; t < 4; ++t) {
            const int ao = t * 4096 + lk * 1024 + (wv * 16 + lr) * 16;
            h8 a1 = *reinterpret_cast<const h8*>(ab + ao);
            h8 a2;
            if (MODE == 0) a2 = *reinterpret_cast<const h8*>(ab + 16384 + ao);
            #pragma unroll
            for (int ni = 0; ni < 4; ++ni) {
                accA[t][ni] = __builtin_amdgcn_mfma_f32_16x16x32_f16(a1, wf1[ni], accA[t][ni], 0, 0, 0);
                accB[t][ni] = __builtin_amdgcn_mfma_f32_16x16x32_f16(a1, wf2[ni], accB[t][ni], 0, 0, 0);
                if (MODE == 0)
                    accB[t][ni] = __builtin_amdgcn_mfma_f32_16x16x32_f16(a2, wf1[ni], accB[t][ni], 0, 0, 0);
            }
        }
    }

    // ---- in-register BN + LIF epilogue (wave owns all 4 t of its rows) ----
    #pragma unroll
    for (int ni = 0; ni < 4; ++ni) {
        const int c = col0 + ni * 16 + lr;
        const float sc = gam[c] * (1.0f / sqrtf(rva[c] + EPSf));
        const float bi = bias[c], mn = mea[c], be = bet[c];
        #pragma unroll
        for (int r = 0; r < 4; ++r) {
            const int bn = row0 + wv * 16 + lk * 4 + r;  // C/D: row=(l>>4)*4+reg, col=l&15
            float vm = 0.0f;
            #pragma unroll
            for (int t = 0; t < 4; ++t) {
                const float res = accA[t][ni][r] + INV4096 * accB[t][ni][r];
                const float y = ((res + bi) - mn) * sc + be;
                vm = vm + (y - vm) * 0.5f;
                const float s = (vm >= 1.0f) ? 1.0f : 0.0f;
                vm = (s != 0.0f) ? 0.0f : vm;
                if (MODE == 0) {
                    const int b = bn >> 9, n = bn & 511;
                    out_hs[((((size_t)t * B_ + b) * H_ + ct) * N_ + n) * D_ + ni * 16 + lr] =
                        __float2bfloat16(s);
                } else {
                    out_plain[((size_t)t * BNR + bn) * C_ + c] = s;
                }
            }
        }
    }
}

// ---- kv[d1][d2] = sum_n k[n,d1]*v[n,d2] per (t,b,h) ----
__global__ __launch_bounds__(256)
void ktv_kernel(const __hip_bfloat16* __restrict__ sk, const __hip_bfloat16* __restrict__ sv,
                float* __restrict__ kv)
{
    __shared__ __hip_bfloat16 kl[64][64];
    __shared__ __hip_bfloat16 vl[64][64];
    const int tbh = blockIdx.x;
    const int tid = threadIdx.x;
    const int tx = tid & 15, ty = tid >> 4;
    const size_t base = (size_t)tbh * N_ * D_;
    float acc[4][4] = {};
    for (int n0 = 0; n0 < N_; n0 += 64) {
        __syncthreads();
        #pragma unroll
        for (int p = 0; p < 2; ++p) {
            const int idx = tid + p * 256;
            const int r = idx >> 3, c8 = (idx & 7) * 8;
            *reinterpret_cast<float4*>(&kl[r][c8]) =
                *reinterpret_cast<const float4*>(&sk[base + (size_t)(n0 + r) * D_ + c8]);
            *reinterpret_cast<float4*>(&vl[r][c8]) =
                *reinterpret_cast<const float4*>(&sv[base + (size_t)(n0 + r) * D_ + c8]);
        }
        __syncthreads();
        for (int nn = 0; nn < 64; ++nn) {
            float a[4], b[4];
            #pragma unroll
            for (int i = 0; i < 4; ++i) a[i] = __bfloat162float(kl[nn][ty * 4 + i]);
            #pragma unroll
            for (int j = 0; j < 4; ++j) b[j] = __bfloat162float(vl[nn][tx * 4 + j]);
            #pragma unroll
            for (int i = 0; i < 4; ++i)
                #pragma unroll
                for (int j = 0; j < 4; ++j)
                    acc[i][j] = fmaf(a[i], b[j], acc[i][j]);
        }
    }
    float* out = kv + (size_t)tbh * 4096;
    #pragma unroll
    for (int i = 0; i < 4; ++i)
        #pragma unroll
        for (int j = 0; j < 4; ++j)
            out[(ty * 4 + i) * 64 + tx * 4 + j] = acc[i][j];
}

// ---- o = 0.125 * q @ kv, fused attn-LIF (vth=0.5); writes f16 spikes (T,B,N,C) ----
__global__ __launch_bounds__(256)
void qkv_lif_kernel(const __hip_bfloat16* __restrict__ sq, const float* __restrict__ kv,
                    _Float16* __restrict__ osp)
{
    __shared__ float kvl[64][64];
    __shared__ __hip_bfloat16 ql[64][64];
    const int nt = blockIdx.x, b = blockIdx.y, h = blockIdx.z;
    const int tid = threadIdx.x;
    const int tx = tid & 15, ty = tid >> 4;
    const int n0 = nt * 64;
    float v[4][4] = {};
    for (int t = 0; t < T_; ++t) {
        const int tbh = (t * B_ + b) * H_ + h;
        __syncthreads();
        #pragma unroll
        for (int p = 0; p < 16; ++p) {
            const int idx = p * 256 + tid;
            kvl[idx >> 6][idx & 63] = kv[(size_t)tbh * 4096 + idx];
        }
        #pragma unroll
        for (int p = 0; p < 2; ++p) {
            const int idx = tid + p * 256;
            const int r = idx >> 3, c8 = (idx & 7) * 8;
            *reinterpret_cast<float4*>(&ql[r][c8]) =
                *reinterpret_cast<const float4*>(&sq[((size_t)tbh * N_ + n0 + r) * D_ + c8]);
        }
        __syncthreads();
        float acc[4][4] = {};
        for (int dd = 0; dd < 64; ++dd) {
            float a[4], bb[4];
            #pragma unroll
            for (int i = 0; i < 4; ++i) a[i] = __bfloat162float(ql[ty * 4 + i][dd]);
            #pragma unroll
            for (int j = 0; j < 4; ++j) bb[j] = kvl[dd][tx * 4 + j];
            #pragma unroll
            for (int i = 0; i < 4; ++i)
                #pragma unroll
                for (int j = 0; j < 4; ++j)
                    acc[i][j] = fmaf(a[i], bb[j], acc[i][j]);
        }
        #pragma unroll
        for (int i = 0; i < 4; ++i)
            #pragma unroll
            for (int j = 0; j < 4; ++j) {
                const float y = 0.125f * acc[i][j];     // exact (integer counts)
                float vv = v[i][j];
                vv = vv + (y - vv) * 0.5f;
                const float s = (vv >= 0.5f) ? 1.0f : 0.0f;
                osp[((size_t)(t * B_ + b) * N_ + n0 + ty * 4 + i) * C_ + h * 64 + tx * 4 + j] = (_Float16)s;
                v[i][j] = (s != 0.0f) ? 0.0f : vv;
            }
    }
}

extern "C" void kernel_launch(void* const* d_in, const int* in_sizes, int n_in,
                              void* d_out, int out_size, void* d_ws, size_t ws_size,
                              hipStream_t stream)
{
    const float* x = (const float*)d_in[0];
    const float *W[4], *bia[4], *gam[4], *bet[4], *mea[4], *rva[4];
    for (int br = 0; br < 4; ++br) {
        W[br]   = (const float*)d_in[1 + 6 * br + 0];
        bia[br] = (const float*)d_in[1 + 6 * br + 1];
        gam[br] = (const float*)d_in[1 + 6 * br + 2];
        bet[br] = (const float*)d_in[1 + 6 * br + 3];
        mea[br] = (const float*)d_in[1 + 6 * br + 4];
        rva[br] = (const float*)d_in[1 + 6 * br + 5];
    }
    char* ws = (char*)d_ws;
    _Float16* x1 = (_Float16*)(ws + 0);
    _Float16* x2 = (_Float16*)(ws + 16777216);
    __hip_bfloat16* sq = (__hip_bfloat16*)(ws + 33554432);
    __hip_bfloat16* sk = (__hip_bfloat16*)(ws + 50331648);
    __hip_bfloat16* sv = (__hip_bfloat16*)(ws + 67108864);
    _Float16* w1[4], *w2[4];
    for (int br = 0; br < 4; ++br) {
        w1[br] = (_Float16*)(ws + 83886080 + (size_t)br * 1048576);
        w2[br] = (_Float16*)(ws + 83886080 + (size_t)br * 1048576 + 524288);
    }
    float*    kv  = (float*)(ws + 16777216);     // aliases x2 (dead after 3rd GEMM)
    _Float16* osp = (_Float16*)(ws + 0);         // aliases x1 (dead after 3rd GEMM)

    dim3 blk(256);
    split_f16<<<dim3(8192), blk, 0, stream>>>(x, x1, x2, 2097152);
    for (int br = 0; br < 4; ++br)
        pack_w<<<dim3(128), blk, 0, stream>>>(W[br], w1[br], w2[br]);

    mfma_gemm_bn_lif<0><<<dim3(512), blk, 0, stream>>>(x1, x2, w1[0], w2[0],
        bia[0], gam[0], bet[0], mea[0], rva[0], sq, nullptr);
    mfma_gemm_bn_lif<0><<<dim3(512), blk, 0, stream>>>(x1, x2, w1[1], w2[1],
        bia[1], gam[1], bet[1], mea[1], rva[1], sk, nullptr);
    mfma_gemm_bn_lif<0><<<dim3(512), blk, 0, stream>>>(x1, x2, w1[2], w2[2],
        bia[2], gam[2], bet[2], mea[2], rva[2], sv, nullptr);

    ktv_kernel<<<dim3(T_ * B_ * H_), blk, 0, stream>>>(sk, sv, kv);
    qkv_lif_kernel<<<dim3(N_ / 64, B_, H_), blk, 0, stream>>>(sq, kv, osp);

    mfma_gemm_bn_lif<1><<<dim3(512), blk, 0, stream>>>(osp, nullptr, w1[3], w2[3],
        bia[3], gam[3], bet[3], mea[3], rva[3], nullptr, (float*)d_out);
}

// Round 6
// 192.700 us; speedup vs baseline: 1.8008x; 1.1403x over previous
//
#include <hip/hip_runtime.h>
#include <hip/hip_bf16.h>

typedef _Float16 h8 __attribute__((ext_vector_type(8)));
typedef _Float16 h4v __attribute__((ext_vector_type(4)));
typedef float f4 __attribute__((ext_vector_type(4)));

#define T_ 4
#define B_ 8
#define N_ 512
#define C_ 512
#define H_ 8
#define D_ 64
#define BNR 4096
#define EPSf 1e-5f
#define F16_MIN_NORM 6.1035156e-05f
#define INV4096 0.000244140625f

// ---- x -> (h1 + 2^-12 * h2) f16 split, packed MFMA-fragment-linear ----
// A1p/A2p[rt][t][ks][lane][8]: lane l holds x[t][rt*16 + (l&15)][ks*32 + (l>>4)*8 ..+8]
// so a GEMM A-frag load is 64 lanes x 16B CONTIGUOUS (1KB coalesced).
__global__ __launch_bounds__(256)
void split_pack_x(const float* __restrict__ in, _Float16* __restrict__ h1,
                  _Float16* __restrict__ h2)
{
    const int gid = blockIdx.x * 256 + threadIdx.x;    // 1048576 h8-groups
    const int lane = gid & 63;
    const int ks = (gid >> 6) & 15;
    const int t = (gid >> 10) & 3;
    const int rt = gid >> 12;
    const int row = rt * 16 + (lane & 15);
    const size_t src = ((size_t)t * BNR + row) * C_ + ks * 32 + (lane >> 4) * 8;
    const float4 x0 = *reinterpret_cast<const float4*>(in + src);
    const float4 x1 = *reinterpret_cast<const float4*>(in + src + 4);
    h8 a, b;
    #pragma unroll
    for (int j = 0; j < 8; ++j) {
        const float xv = (j < 4) ? (&x0.x)[j] : (&x1.x)[j - 4];
        const float hi = (fabsf(xv) >= F16_MIN_NORM) ? xv : 0.0f;  // no subnormal x1
        const _Float16 h = (_Float16)hi;
        const float r = (xv - (float)h) * 4096.0f;                 // normal-range residual
        a[j] = h; b[j] = (_Float16)r;
    }
    *reinterpret_cast<h8*>(h1 + (size_t)gid * 8) = a;
    *reinterpret_cast<h8*>(h2 + (size_t)gid * 8) = b;
}

// ---- W -> split + MFMA-fragment-linear pack ----
// Wp[ct][ks][ni][lane][8]: lane l holds W[(ct*64+ni*16+(l&15))*512 + ks*32+(l>>4)*8 ..+8]
__global__ __launch_bounds__(256)
void pack_w(const float* __restrict__ W, _Float16* __restrict__ Wp1,
            _Float16* __restrict__ Wp2)
{
    const int gid = blockIdx.x * 256 + threadIdx.x;   // 32768 items
    const int lane = gid & 63;
    const int ni = (gid >> 6) & 3;
    const int ks = (gid >> 8) & 15;
    const int ct = gid >> 12;
    const int col = ct * 64 + ni * 16 + (lane & 15);
    const int k = ks * 32 + (lane >> 4) * 8;
    const float* src = W + (size_t)col * C_ + k;
    h8 a, b;
    #pragma unroll
    for (int j = 0; j < 8; ++j) {
        const float xv = src[j];
        const float hi = (fabsf(xv) >= F16_MIN_NORM) ? xv : 0.0f;
        const _Float16 h = (_Float16)hi;
        const float r = (xv - (float)h) * 4096.0f;
        a[j] = h; b[j] = (_Float16)r;
    }
    *reinterpret_cast<h8*>(Wp1 + (size_t)gid * 8) = a;
    *reinterpret_cast<h8*>(Wp2 + (size_t)gid * 8) = b;
}

// ---- LDS-free MFMA GEMM (f16 split) + BN(eval) + LIF over T ----
// Block: 4 independent waves. Wave w: rows [bt*64+16w, +16) x 64 cols x all 4 t.
// Both operands read fragment-linear from global (coalesced 1KB dwordx4) ->
// no LDS, no barriers; waves slip freely, compiler pipelines the reg loads.
// MODE 0: A=(A1p,A2p) split, 3 mfma/frag, out bf16 head-split (T,B,H,N,D).
// MODE 1: A=A1p exact f16 spikes, 2 mfma/frag, out fp32 (T,B,N,C).
template<int MODE>
__global__ __launch_bounds__(256, 2)
void mfma_gemm_bn_lif(const _Float16* __restrict__ A1p, const _Float16* __restrict__ A2p,
                      const _Float16* __restrict__ Wp1, const _Float16* __restrict__ Wp2,
                      const float* __restrict__ bias, const float* __restrict__ gam,
                      const float* __restrict__ bet, const float* __restrict__ mea,
                      const float* __restrict__ rva,
                      __hip_bfloat16* __restrict__ out_hs, float* __restrict__ out_plain)
{
    const int id = blockIdx.x;
    const int bt = (id & 7) * 8 + ((id >> 3) & 7);      // XCD-aware swizzle
    const int ct = id >> 6;
    const int wv = threadIdx.x >> 6, lane = threadIdx.x & 63;
    const int rt = bt * 4 + wv;                         // 16-row tile index
    const int row0 = bt * 64, col0 = ct * 64;
    const int lr = lane & 15, lk = lane >> 4;

    f4 accA[4][4], accB[4][4];                          // [t][ni]
    #pragma unroll
    for (int t = 0; t < 4; ++t)
        #pragma unroll
        for (int ni = 0; ni < 4; ++ni) { accA[t][ni] = (f4)0.0f; accB[t][ni] = (f4)0.0f; }

    const _Float16* aB1 = A1p + (size_t)rt * (4 * 16 * 512) + lane * 8;
    const _Float16* aB2 = (MODE == 0) ? A2p + (size_t)rt * (4 * 16 * 512) + lane * 8 : nullptr;
    const _Float16* wB1 = Wp1 + (size_t)ct * (16 * 4 * 512) + lane * 8;
    const _Float16* wB2 = Wp2 + (size_t)ct * (16 * 4 * 512) + lane * 8;

    #pragma unroll 2
    for (int ks = 0; ks < 16; ++ks) {
        h8 wf1[4], wf2[4];
        #pragma unroll
        for (int ni = 0; ni < 4; ++ni) {
            wf1[ni] = *reinterpret_cast<const h8*>(wB1 + (ks * 4 + ni) * 512);
            wf2[ni] = *reinterpret_cast<const h8*>(wB2 + (ks * 4 + ni) * 512);
        }
        #pragma unroll
        for (int t = 0; t < 4; ++t) {
            const h8 a1 = *reinterpret_cast<const h8*>(aB1 + (t * 16 + ks) * 512);
            h8 a2;
            if (MODE == 0) a2 = *reinterpret_cast<const h8*>(aB2 + (t * 16 + ks) * 512);
            #pragma unroll
            for (int ni = 0; ni < 4; ++ni) {
                accA[t][ni] = __builtin_amdgcn_mfma_f32_16x16x32_f16(a1, wf1[ni], accA[t][ni], 0, 0, 0);
                accB[t][ni] = __builtin_amdgcn_mfma_f32_16x16x32_f16(a1, wf2[ni], accB[t][ni], 0, 0, 0);
                if (MODE == 0)
                    accB[t][ni] = __builtin_amdgcn_mfma_f32_16x16x32_f16(a2, wf1[ni], accB[t][ni], 0, 0, 0);
            }
        }
    }

    // ---- in-register BN + LIF epilogue (wave owns all 4 t of its rows) ----
    #pragma unroll
    for (int ni = 0; ni < 4; ++ni) {
        const int c = col0 + ni * 16 + lr;
        const float sc = gam[c] * (1.0f / sqrtf(rva[c] + EPSf));
        const float bi = bias[c], mn = mea[c], be = bet[c];
        #pragma unroll
        for (int r = 0; r < 4; ++r) {
            const int bn = row0 + wv * 16 + lk * 4 + r;  // C/D: row=(l>>4)*4+reg, col=l&15
            float vm = 0.0f;
            #pragma unroll
            for (int t = 0; t < 4; ++t) {
                const float res = accA[t][ni][r] + INV4096 * accB[t][ni][r];
                const float y = ((res + bi) - mn) * sc + be;
                vm = vm + (y - vm) * 0.5f;
                const float s = (vm >= 1.0f) ? 1.0f : 0.0f;
                vm = (s != 0.0f) ? 0.0f : vm;
                if (MODE == 0) {
                    const int b = bn >> 9, n = bn & 511;
                    out_hs[((((size_t)t * B_ + b) * H_ + ct) * N_ + n) * D_ + ni * 16 + lr] =
                        __float2bfloat16(s);
                } else {
                    out_plain[((size_t)t * BNR + bn) * C_ + c] = s;
                }
            }
        }
    }
}

// ---- kv[d1][d2] = sum_n k[n,d1]*v[n,d2] per (t,b,h) ----
__global__ __launch_bounds__(256)
void ktv_kernel(const __hip_bfloat16* __restrict__ sk, const __hip_bfloat16* __restrict__ sv,
                float* __restrict__ kv)
{
    __shared__ __hip_bfloat16 kl[64][64];
    __shared__ __hip_bfloat16 vl[64][64];
    const int tbh = blockIdx.x;
    const int tid = threadIdx.x;
    const int tx = tid & 15, ty = tid >> 4;
    const size_t base = (size_t)tbh * N_ * D_;
    float acc[4][4] = {};
    for (int n0 = 0; n0 < N_; n0 += 64) {
        __syncthreads();
        #pragma unroll
        for (int p = 0; p < 2; ++p) {
            const int idx = tid + p * 256;
            const int r = idx >> 3, c8 = (idx & 7) * 8;
            *reinterpret_cast<float4*>(&kl[r][c8]) =
                *reinterpret_cast<const float4*>(&sk[base + (size_t)(n0 + r) * D_ + c8]);
            *reinterpret_cast<float4*>(&vl[r][c8]) =
                *reinterpret_cast<const float4*>(&sv[base + (size_t)(n0 + r) * D_ + c8]);
        }
        __syncthreads();
        for (int nn = 0; nn < 64; ++nn) {
            float a[4], b[4];
            #pragma unroll
            for (int i = 0; i < 4; ++i) a[i] = __bfloat162float(kl[nn][ty * 4 + i]);
            #pragma unroll
            for (int j = 0; j < 4; ++j) b[j] = __bfloat162float(vl[nn][tx * 4 + j]);
            #pragma unroll
            for (int i = 0; i < 4; ++i)
                #pragma unroll
                for (int j = 0; j < 4; ++j)
                    acc[i][j] = fmaf(a[i], b[j], acc[i][j]);
        }
    }
    float* out = kv + (size_t)tbh * 4096;
    #pragma unroll
    for (int i = 0; i < 4; ++i)
        #pragma unroll
        for (int j = 0; j < 4; ++j)
            out[(ty * 4 + i) * 64 + tx * 4 + j] = acc[i][j];
}

// ---- o = 0.125 * q @ kv, fused attn-LIF (vth=0.5) ----
// Writes f16 spikes directly in MFMA-fragment-packed layout (A1p for MODE1 GEMM).
__global__ __launch_bounds__(256)
void qkv_lif_kernel(const __hip_bfloat16* __restrict__ sq, const float* __restrict__ kv,
                    _Float16* __restrict__ osp)
{
    __shared__ float kvl[64][64];
    __shared__ __hip_bfloat16 ql[64][64];
    const int nt = blockIdx.x, b = blockIdx.y, h = blockIdx.z;
    const int tid = threadIdx.x;
    const int tx = tid & 15, ty = tid >> 4;
    const int n0 = nt * 64;
    float v[4][4] = {};
    for (int t = 0; t < T_; ++t) {
        const int tbh = (t * B_ + b) * H_ + h;
        __syncthreads();
        #pragma unroll
        for (int p = 0; p < 16; ++p) {
            const int idx = p * 256 + tid;
            kvl[idx >> 6][idx & 63] = kv[(size_t)tbh * 4096 + idx];
        }
        #pragma unroll
        for (int p = 0; p < 2; ++p) {
            const int idx = tid + p * 256;
            const int r = idx >> 3, c8 = (idx & 7) * 8;
            *reinterpret_cast<float4*>(&ql[r][c8]) =
                *reinterpret_cast<const float4*>(&sq[((size_t)tbh * N_ + n0 + r) * D_ + c8]);
        }
        __syncthreads();
        float acc[4][4] = {};
        for (int dd = 0; dd < 64; ++dd) {
            float a[4], bb[4];
            #pragma unroll
            for (int i = 0; i < 4; ++i) a[i] = __bfloat162float(ql[ty * 4 + i][dd]);
            #pragma unroll
            for (int j = 0; j < 4; ++j) bb[j] = kvl[dd][tx * 4 + j];
            #pragma unroll
            for (int i = 0; i < 4; ++i)
                #pragma unroll
                for (int j = 0; j < 4; ++j)
                    acc[i][j] = fmaf(a[i], bb[j], acc[i][j]);
        }
        // packed-layout write: row_bn = b*N + n, c = h*64 + tx*4 + j
        #pragma unroll
        for (int i = 0; i < 4; ++i) {
            const int row_bn = b * N_ + n0 + ty * 4 + i;
            const int c0 = h * 64 + tx * 4;
            const int rt = row_bn >> 4, rlo = row_bn & 15;
            const int ks = c0 >> 5, lk3 = (c0 >> 3) & 3, j0 = c0 & 7;
            h4v sp;
            #pragma unroll
            for (int j = 0; j < 4; ++j) {
                const float y = 0.125f * acc[i][j];     // exact (integer counts)
                float vv = v[i][j];
                vv = vv + (y - vv) * 0.5f;
                const float s = (vv >= 0.5f) ? 1.0f : 0.0f;
                sp[j] = (_Float16)s;
                v[i][j] = (s != 0.0f) ? 0.0f : vv;
            }
            _Float16* dst = osp + ((((size_t)rt * 4 + t) * 16 + ks) * 64 + lk3 * 16 + rlo) * 8 + j0;
            *reinterpret_cast<h4v*>(dst) = sp;
        }
    }
}

extern "C" void kernel_launch(void* const* d_in, const int* in_sizes, int n_in,
                              void* d_out, int out_size, void* d_ws, size_t ws_size,
                              hipStream_t stream)
{
    const float* x = (const float*)d_in[0];
    const float *W[4], *bia[4], *gam[4], *bet[4], *mea[4], *rva[4];
    for (int br = 0; br < 4; ++br) {
        W[br]   = (const float*)d_in[1 + 6 * br + 0];
        bia[br] = (const float*)d_in[1 + 6 * br + 1];
        gam[br] = (const float*)d_in[1 + 6 * br + 2];
        bet[br] = (const float*)d_in[1 + 6 * br + 3];
        mea[br] = (const float*)d_in[1 + 6 * br + 4];
        rva[br] = (const float*)d_in[1 + 6 * br + 5];
    }
    char* ws = (char*)d_ws;
    _Float16* x1 = (_Float16*)(ws + 0);
    _Float16* x2 = (_Float16*)(ws + 16777216);
    __hip_bfloat16* sq = (__hip_bfloat16*)(ws + 33554432);
    __hip_bfloat16* sk = (__hip_bfloat16*)(ws + 50331648);
    __hip_bfloat16* sv = (__hip_bfloat16*)(ws + 67108864);
    _Float16* w1[4], *w2[4];
    for (int br = 0; br < 4; ++br) {
        w1[br] = (_Float16*)(ws + 83886080 + (size_t)br * 1048576);
        w2[br] = (_Float16*)(ws + 83886080 + (size_t)br * 1048576 + 524288);
    }
    float*    kv  = (float*)(ws + 16777216);     // aliases x2 (dead after 3rd GEMM)
    _Float16* osp = (_Float16*)(ws + 0);         // aliases x1 (dead after 3rd GEMM)

    dim3 blk(256);
    split_pack_x<<<dim3(4096), blk, 0, stream>>>(x, x1, x2);
    for (int br = 0; br < 4; ++br)
        pack_w<<<dim3(128), blk, 0, stream>>>(W[br], w1[br], w2[br]);

    mfma_gemm_bn_lif<0><<<dim3(512), blk, 0, stream>>>(x1, x2, w1[0], w2[0],
        bia[0], gam[0], bet[0], mea[0], rva[0], sq, nullptr);
    mfma_gemm_bn_lif<0><<<dim3(512), blk, 0, stream>>>(x1, x2, w1[1], w2[1],
        bia[1], gam[1], bet[1], mea[1], rva[1], sk, nullptr);
    mfma_gemm_bn_lif<0><<<dim3(512), blk, 0, stream>>>(x1, x2, w1[2], w2[2],
        bia[2], gam[2], bet[2], mea[2], rva[2], sv, nullptr);

    ktv_kernel<<<dim3(T_ * B_ * H_), blk, 0, stream>>>(sk, sv, kv);
    qkv_lif_kernel<<<dim3(N_ / 64, B_, H_), blk, 0, stream>>>(sq, kv, osp);

    mfma_gemm_bn_lif<1><<<dim3(512), blk, 0, stream>>>(osp, nullptr, w1[3], w2[3],
        bia[3], gam[3], bet[3], mea[3], rva[3], nullptr, (float*)d_out);
}